// Round 1
// baseline (63.074 us; speedup 1.0000x reference)
//
#include <hip/hip_runtime.h>
#include <stdint.h>

#define NQ 8
#define DIM 256
#define BSZ 32768
#define NOPS 20

struct OpList { int kind[NOPS]; int w0[NOPS]; int w1[NOPS]; };

// ---------------- device side ----------------

__device__ __forceinline__ float shflx(float v, int mask) { return __shfl_xor(v, mask, 64); }

// Layout: amplitude index d = (j<<4) | l, j = per-lane register index 0..15,
// l = lane-in-group 0..15. Wire w has bit mask m = 1<<(7-w) in d.
// m >= 16  -> in-lane pair (j0, j0|M), M = m>>4
// m <  16  -> cross-lane partner via shfl_xor(m)

template<int W>
__device__ __forceinline__ void apply_rx(float (&vr)[16], float (&vi)[16], int l, float c, float s) {
  constexpr int m = 1 << (7 - W);
  if constexpr (m >= 16) {
    constexpr int M = m >> 4;
    #pragma unroll
    for (int j0 = 0; j0 < 16; ++j0) {
      if ((j0 & M) == 0) {
        const int j1 = j0 | M;
        float r0 = vr[j0], i0 = vi[j0], r1 = vr[j1], i1 = vi[j1];
        // n = c*self - i*s*partner   (same form for both halves)
        vr[j0] = fmaf(s, i1, c * r0);
        vi[j0] = fmaf(-s, r1, c * i0);
        vr[j1] = fmaf(s, i0, c * r1);
        vi[j1] = fmaf(-s, r0, c * i1);
      }
    }
  } else {
    #pragma unroll
    for (int j = 0; j < 16; ++j) {
      float xr = shflx(vr[j], m), xi = shflx(vi[j], m);
      vr[j] = fmaf(s, xi, c * vr[j]);
      vi[j] = fmaf(-s, xr, c * vi[j]);
    }
  }
}

template<int W>
__device__ __forceinline__ void apply_ry(float (&vr)[16], float (&vi)[16], int l, float c, float s) {
  constexpr int m = 1 << (7 - W);
  if constexpr (m >= 16) {
    constexpr int M = m >> 4;
    #pragma unroll
    for (int j0 = 0; j0 < 16; ++j0) {
      if ((j0 & M) == 0) {
        const int j1 = j0 | M;
        float r0 = vr[j0], i0 = vi[j0], r1 = vr[j1], i1 = vi[j1];
        vr[j0] = fmaf(-s, r1, c * r0);
        vi[j0] = fmaf(-s, i1, c * i0);
        vr[j1] = fmaf(s, r0, c * r1);
        vi[j1] = fmaf(s, i0, c * i1);
      }
    }
  } else {
    const float t = (l & m) ? s : -s;   // bit0: c*self - s*partner ; bit1: c*self + s*partner
    #pragma unroll
    for (int j = 0; j < 16; ++j) {
      float xr = shflx(vr[j], m), xi = shflx(vi[j], m);
      vr[j] = fmaf(t, xr, c * vr[j]);
      vi[j] = fmaf(t, xi, c * vi[j]);
    }
  }
}

// RZ is diagonal -> no data movement, works for any wire with runtime mask.
__device__ __forceinline__ void apply_rz_rt(int w, float (&vr)[16], float (&vi)[16], int l, float c, float s) {
  const int m = 1 << (7 - w);
  #pragma unroll
  for (int j = 0; j < 16; ++j) {
    const float t = ((((j << 4) | l) & m) != 0) ? s : -s;  // bit0: *(c-is), bit1: *(c+is)
    float r = vr[j], ii = vi[j];
    vr[j] = fmaf(-t, ii, c * r);
    vi[j] = fmaf(t, r, c * ii);
  }
}

__device__ __forceinline__ void apply_rot_rt(int kind, int w, float (&vr)[16], float (&vi)[16], int l, float c, float s) {
  switch (w) {
    case 0: if (kind == 0) apply_rx<0>(vr, vi, l, c, s); else apply_ry<0>(vr, vi, l, c, s); break;
    case 1: if (kind == 0) apply_rx<1>(vr, vi, l, c, s); else apply_ry<1>(vr, vi, l, c, s); break;
    case 2: if (kind == 0) apply_rx<2>(vr, vi, l, c, s); else apply_ry<2>(vr, vi, l, c, s); break;
    case 3: if (kind == 0) apply_rx<3>(vr, vi, l, c, s); else apply_ry<3>(vr, vi, l, c, s); break;
    case 4: if (kind == 0) apply_rx<4>(vr, vi, l, c, s); else apply_ry<4>(vr, vi, l, c, s); break;
    case 5: if (kind == 0) apply_rx<5>(vr, vi, l, c, s); else apply_ry<5>(vr, vi, l, c, s); break;
    case 6: if (kind == 0) apply_rx<6>(vr, vi, l, c, s); else apply_ry<6>(vr, vi, l, c, s); break;
    default: if (kind == 0) apply_rx<7>(vr, vi, l, c, s); else apply_ry<7>(vr, vi, l, c, s); break;
  }
}

template<int M>
__device__ __forceinline__ void cnot_inlane(float (&vr)[16], float (&vi)[16], int l, int mc) {
  #pragma unroll
  for (int j0 = 0; j0 < 16; ++j0) {
    if ((j0 & M) == 0) {
      const int j1 = j0 | M;
      const bool bit = ((((j0 << 4) | l) & mc) != 0);  // control bit (same for j0,j1)
      float r0 = vr[j0], r1 = vr[j1];
      vr[j0] = bit ? r1 : r0; vr[j1] = bit ? r0 : r1;
      float i0 = vi[j0], i1 = vi[j1];
      vi[j0] = bit ? i1 : i0; vi[j1] = bit ? i0 : i1;
    }
  }
}

__device__ __forceinline__ void apply_cnot_rt(int wc, int wt, float (&vr)[16], float (&vi)[16], int l) {
  const int mc = 1 << (7 - wc);
  switch (wt) {
    case 0: cnot_inlane<8>(vr, vi, l, mc); break;
    case 1: cnot_inlane<4>(vr, vi, l, mc); break;
    case 2: cnot_inlane<2>(vr, vi, l, mc); break;
    case 3: cnot_inlane<1>(vr, vi, l, mc); break;
    default: {
      const int mt = 1 << (7 - wt);   // < 16: cross-lane swap
      #pragma unroll
      for (int j = 0; j < 16; ++j) {
        float xr = shflx(vr[j], mt), xi = shflx(vi[j], mt);
        const bool bit = ((((j << 4) | l) & mc) != 0);
        vr[j] = bit ? xr : vr[j];
        vi[j] = bit ? xi : vi[j];
      }
      break;
    }
  }
}

__global__ __launch_bounds__(256)
void qcnn_kernel(const float* __restrict__ x, const float* __restrict__ rl,
                 const float* __restrict__ thx, const float* __restrict__ thy,
                 float* __restrict__ out, OpList ops)
{
  const int tid = blockIdx.x * blockDim.x + threadIdx.x;
  const int b = tid >> 4;    // sample
  const int l = tid & 15;    // lane-in-group

  float vr[16], vi[16];

  // ---- layer 1: 8 per-sample RYs on |0...0> == product state, built directly ----
  float cw[8], sw[8];
  #pragma unroll
  for (int w = 0; w < 8; ++w) {
    const float a = x[b * 8 + w] * 0.5f;
    sw[w] = __sinf(a); cw[w] = __cosf(a);
  }
  // d bits: wire0..3 <- j bits 3..0 ; wire4..7 <- l bits 3..0
  const float pl = ((l & 8) ? sw[4] : cw[4]) * ((l & 4) ? sw[5] : cw[5]) *
                   ((l & 2) ? sw[6] : cw[6]) * ((l & 1) ? sw[7] : cw[7]);
  #pragma unroll
  for (int j = 0; j < 16; ++j) {
    const float ph = ((j & 8) ? sw[0] : cw[0]) * ((j & 4) ? sw[1] : cw[1]) *
                     ((j & 2) ? sw[2] : cw[2]) * ((j & 1) ? sw[3] : cw[3]);
    vr[j] = ph * pl; vi[j] = 0.0f;
  }

  // ---- 20 RL ops (host-decoded, wave-uniform dispatch) ----
  for (int k = 0; k < NOPS; ++k) {
    const int kind = ops.kind[k];
    if (kind == 3) {
      apply_cnot_rt(ops.w0[k], ops.w1[k], vr, vi, l);
    } else {
      const float a = rl[k] * 0.5f;
      const float sn = __sinf(a), cs = __cosf(a);
      if (kind == 2) apply_rz_rt(ops.w0[k], vr, vi, l, cs, sn);
      else           apply_rot_rt(kind, ops.w0[k], vr, vi, l, cs, sn);
    }
  }

  // ---- final layer: per wire RX(theta_rx) then RY(theta_ry) ----
  {
    const float ax = thx[0] * 0.5f, ay = thy[0] * 0.5f;
    const float sx = __sinf(ax), cx = __cosf(ax);
    const float sy = __sinf(ay), cy = __cosf(ay);
    apply_rx<0>(vr, vi, l, cx, sx); apply_ry<0>(vr, vi, l, cy, sy);
    apply_rx<1>(vr, vi, l, cx, sx); apply_ry<1>(vr, vi, l, cy, sy);
    apply_rx<2>(vr, vi, l, cx, sx); apply_ry<2>(vr, vi, l, cy, sy);
    apply_rx<3>(vr, vi, l, cx, sx); apply_ry<3>(vr, vi, l, cy, sy);
    apply_rx<4>(vr, vi, l, cx, sx); apply_ry<4>(vr, vi, l, cy, sy);
    apply_rx<5>(vr, vi, l, cx, sx); apply_ry<5>(vr, vi, l, cy, sy);
    apply_rx<6>(vr, vi, l, cx, sx); apply_ry<6>(vr, vi, l, cy, sy);
    apply_rx<7>(vr, vi, l, cx, sx); apply_ry<7>(vr, vi, l, cy, sy);
  }

  // ---- measurement: out[b][q] = sum_d (1 - 2*bit_q(d)) * |amp_d|^2 ----
  float P = 0.f, A0 = 0.f, A1 = 0.f, A2 = 0.f, A3 = 0.f;
  #pragma unroll
  for (int j = 0; j < 16; ++j) {
    const float p = fmaf(vr[j], vr[j], vi[j] * vi[j]);
    P += p;
    A0 += (j & 8) ? -p : p;
    A1 += (j & 4) ? -p : p;
    A2 += (j & 2) ? -p : p;
    A3 += (j & 1) ? -p : p;
  }
  float B4 = (l & 8) ? -P : P;
  float B5 = (l & 4) ? -P : P;
  float B6 = (l & 2) ? -P : P;
  float B7 = (l & 1) ? -P : P;
  #pragma unroll
  for (int m = 1; m < 16; m <<= 1) {
    A0 += shflx(A0, m); A1 += shflx(A1, m); A2 += shflx(A2, m); A3 += shflx(A3, m);
    B4 += shflx(B4, m); B5 += shflx(B5, m); B6 += shflx(B6, m); B7 += shflx(B7, m);
  }
  if (l == 0) {
    float* o = out + b * 8;
    o[0] = A0; o[1] = A1; o[2] = A2; o[3] = A3;
    o[4] = B4; o[5] = B5; o[6] = B6; o[7] = B7;
  }
}

// ---------------- host side: replicate np.random.RandomState(0) op list ----------------

namespace {

struct NpMT {
  uint32_t mt[624];
  int pos;
  explicit NpMT(uint32_t seed) {
    // numpy mt19937_seed (== init_genrand): mt[i]=seed; seed = 1812433253*(seed^(seed>>30)) + i + 1
    for (int i = 0; i < 624; ++i) {
      mt[i] = seed;
      seed = 1812433253u * (seed ^ (seed >> 30)) + (uint32_t)(i + 1);
    }
    pos = 624;
  }
  uint32_t next32() {
    if (pos >= 624) {
      for (int i = 0; i < 624; ++i) {
        uint32_t y = (mt[i] & 0x80000000u) | (mt[(i + 1) % 624] & 0x7fffffffu);
        mt[i] = mt[(i + 397) % 624] ^ (y >> 1) ^ ((y & 1u) ? 0x9908b0dfu : 0u);
      }
      pos = 0;
    }
    uint32_t y = mt[pos++];
    y ^= y >> 11;
    y ^= (y << 7) & 0x9d2c5680u;
    y ^= (y << 15) & 0xefc60000u;
    y ^= y >> 18;
    return y;
  }
  // legacy masked-rejection bounded draw on 32-bit stream (rk_interval / random_interval)
  uint32_t interval(uint32_t mx) {  // uniform in [0, mx] inclusive
    if (mx == 0u) return 0u;
    uint32_t mask = mx;
    mask |= mask >> 1; mask |= mask >> 2; mask |= mask >> 4; mask |= mask >> 8; mask |= mask >> 16;
    uint32_t v;
    do { v = next32() & mask; } while (v > mx);
    return v;
  }
};

void decode_ops(OpList& ops) {
  NpMT r(0u);
  for (int k = 0; k < NOPS; ++k) {
    const uint32_t kind = r.interval(3u);          // randint(4): one masked 32-bit draw
    ops.kind[k] = (int)kind;
    if (kind == 3u) {                              // 'cnot' -> choice(8,2,replace=False) == permutation(8)[:2]
      int perm[NQ];
      for (int i = 0; i < NQ; ++i) perm[i] = i;
      for (int i = NQ - 1; i >= 1; --i) {          // legacy shuffle: j = random_interval(i)
        const uint32_t j = r.interval((uint32_t)i);
        const int t = perm[i]; perm[i] = perm[(int)j]; perm[(int)j] = t;
      }
      ops.w0[k] = perm[0];  // control
      ops.w1[k] = perm[1];  // target
    } else {
      ops.w0[k] = (int)r.interval(7u);             // randint(8)
      ops.w1[k] = -1;
    }
  }
}

} // namespace

extern "C" void kernel_launch(void* const* d_in, const int* in_sizes, int n_in,
                              void* d_out, int out_size, void* d_ws, size_t ws_size,
                              hipStream_t stream) {
  const float* x   = (const float*)d_in[0];
  const float* rl  = (const float*)d_in[1];
  const float* thx = (const float*)d_in[2];
  const float* thy = (const float*)d_in[3];
  float* out = (float*)d_out;

  OpList ops;
  decode_ops(ops);  // deterministic on every call

  const int threads = 256;                  // 4 waves, 16 samples per block
  const int blocks = BSZ / (threads / 16);  // 2048
  qcnn_kernel<<<blocks, threads, 0, stream>>>(x, rl, thx, thy, out, ops);
}

// Round 2
// 40.992 us; speedup vs baseline: 1.5387x; 1.5387x over previous
//
#include <hip/hip_runtime.h>
#include <stdint.h>

#define NQ 8
#define DIM 256
#define BSZ 32768
#define NOPS 20

struct OpList { int kind[NOPS]; int w0[NOPS]; int w1[NOPS]; };

// ---------------- device side ----------------

// Cross-lane XOR exchange within 16-lane groups.
// mask 1,2 -> quad_perm DPP; mask 8 -> row_ror:8 DPP ( (l+8)%16 == l^8 );
// mask 4 -> ds_swizzle xor-mode (no DPP encoding exists for xor4).
template<int MASK>
__device__ __forceinline__ float lanex(float v) {
  int i = __builtin_bit_cast(int, v);
  int r;
  if constexpr (MASK == 1)      r = __builtin_amdgcn_update_dpp(0, i, 0xB1, 0xF, 0xF, true);  // quad_perm(1,0,3,2)
  else if constexpr (MASK == 2) r = __builtin_amdgcn_update_dpp(0, i, 0x4E, 0xF, 0xF, true);  // quad_perm(2,3,0,1)
  else if constexpr (MASK == 8) r = __builtin_amdgcn_update_dpp(0, i, 0x128, 0xF, 0xF, true); // row_ror:8
  else                          r = __builtin_amdgcn_ds_swizzle(i, 0x101F);                   // xor4, and=31
  return __builtin_bit_cast(float, r);
}

// Layout: amplitude index d = (j<<4) | l, j = per-lane register index 0..15,
// l = lane-in-group 0..15. Wire w has bit mask m = 1<<(7-w) in d.
// m >= 16 -> in-lane pair (j0, j0|M), M = m>>4 ; m < 16 -> cross-lane via lanex<m>.

template<int W>
__device__ __forceinline__ void apply_rx(float (&vr)[16], float (&vi)[16], int l, float c, float s) {
  constexpr int m = 1 << (7 - W);
  if constexpr (m >= 16) {
    constexpr int M = m >> 4;
    #pragma unroll
    for (int j0 = 0; j0 < 16; ++j0) {
      if ((j0 & M) == 0) {
        const int j1 = j0 | M;
        float r0 = vr[j0], i0 = vi[j0], r1 = vr[j1], i1 = vi[j1];
        vr[j0] = fmaf(s, i1, c * r0);
        vi[j0] = fmaf(-s, r1, c * i0);
        vr[j1] = fmaf(s, i0, c * r1);
        vi[j1] = fmaf(-s, r0, c * i1);
      }
    }
  } else {
    #pragma unroll
    for (int j = 0; j < 16; ++j) {
      float xr = lanex<m>(vr[j]), xi = lanex<m>(vi[j]);
      vr[j] = fmaf(s, xi, c * vr[j]);
      vi[j] = fmaf(-s, xr, c * vi[j]);
    }
  }
}

template<int W>
__device__ __forceinline__ void apply_ry(float (&vr)[16], float (&vi)[16], int l, float c, float s) {
  constexpr int m = 1 << (7 - W);
  if constexpr (m >= 16) {
    constexpr int M = m >> 4;
    #pragma unroll
    for (int j0 = 0; j0 < 16; ++j0) {
      if ((j0 & M) == 0) {
        const int j1 = j0 | M;
        float r0 = vr[j0], i0 = vi[j0], r1 = vr[j1], i1 = vi[j1];
        vr[j0] = fmaf(-s, r1, c * r0);
        vi[j0] = fmaf(-s, i1, c * i0);
        vr[j1] = fmaf(s, r0, c * r1);
        vi[j1] = fmaf(s, i0, c * i1);
      }
    }
  } else {
    const float t = (l & m) ? s : -s;
    #pragma unroll
    for (int j = 0; j < 16; ++j) {
      float xr = lanex<m>(vr[j]), xi = lanex<m>(vi[j]);
      vr[j] = fmaf(t, xr, c * vr[j]);
      vi[j] = fmaf(t, xi, c * vi[j]);
    }
  }
}

// RZ is diagonal -> no data movement, runtime mask fine.
__device__ __forceinline__ void apply_rz_rt(int w, float (&vr)[16], float (&vi)[16], int l, float c, float s) {
  const int m = 1 << (7 - w);
  #pragma unroll
  for (int j = 0; j < 16; ++j) {
    const float t = ((((j << 4) | l) & m) != 0) ? s : -s;
    float r = vr[j], ii = vi[j];
    vr[j] = fmaf(-t, ii, c * r);
    vi[j] = fmaf(t, r, c * ii);
  }
}

__device__ __forceinline__ void apply_rot_rt(int kind, int w, float (&vr)[16], float (&vi)[16], int l, float c, float s) {
  switch (w) {
    case 0: if (kind == 0) apply_rx<0>(vr, vi, l, c, s); else apply_ry<0>(vr, vi, l, c, s); break;
    case 1: if (kind == 0) apply_rx<1>(vr, vi, l, c, s); else apply_ry<1>(vr, vi, l, c, s); break;
    case 2: if (kind == 0) apply_rx<2>(vr, vi, l, c, s); else apply_ry<2>(vr, vi, l, c, s); break;
    case 3: if (kind == 0) apply_rx<3>(vr, vi, l, c, s); else apply_ry<3>(vr, vi, l, c, s); break;
    case 4: if (kind == 0) apply_rx<4>(vr, vi, l, c, s); else apply_ry<4>(vr, vi, l, c, s); break;
    case 5: if (kind == 0) apply_rx<5>(vr, vi, l, c, s); else apply_ry<5>(vr, vi, l, c, s); break;
    case 6: if (kind == 0) apply_rx<6>(vr, vi, l, c, s); else apply_ry<6>(vr, vi, l, c, s); break;
    default: if (kind == 0) apply_rx<7>(vr, vi, l, c, s); else apply_ry<7>(vr, vi, l, c, s); break;
  }
}

template<int M>
__device__ __forceinline__ void cnot_inlane(float (&vr)[16], float (&vi)[16], int l, int mc) {
  #pragma unroll
  for (int j0 = 0; j0 < 16; ++j0) {
    if ((j0 & M) == 0) {
      const int j1 = j0 | M;
      const bool bit = ((((j0 << 4) | l) & mc) != 0);
      float r0 = vr[j0], r1 = vr[j1];
      vr[j0] = bit ? r1 : r0; vr[j1] = bit ? r0 : r1;
      float i0 = vi[j0], i1 = vi[j1];
      vi[j0] = bit ? i1 : i0; vi[j1] = bit ? i0 : i1;
    }
  }
}

template<int MASK>
__device__ __forceinline__ void cnot_cross(float (&vr)[16], float (&vi)[16], int l, int mc) {
  #pragma unroll
  for (int j = 0; j < 16; ++j) {
    float xr = lanex<MASK>(vr[j]), xi = lanex<MASK>(vi[j]);
    const bool bit = ((((j << 4) | l) & mc) != 0);
    vr[j] = bit ? xr : vr[j];
    vi[j] = bit ? xi : vi[j];
  }
}

__device__ __forceinline__ void apply_cnot_rt(int wc, int wt, float (&vr)[16], float (&vi)[16], int l) {
  const int mc = 1 << (7 - wc);
  switch (wt) {
    case 0: cnot_inlane<8>(vr, vi, l, mc); break;
    case 1: cnot_inlane<4>(vr, vi, l, mc); break;
    case 2: cnot_inlane<2>(vr, vi, l, mc); break;
    case 3: cnot_inlane<1>(vr, vi, l, mc); break;
    case 4: cnot_cross<8>(vr, vi, l, mc); break;
    case 5: cnot_cross<4>(vr, vi, l, mc); break;
    case 6: cnot_cross<2>(vr, vi, l, mc); break;
    default: cnot_cross<1>(vr, vi, l, mc); break;
  }
}

// ---- direct expectation of M = nx*X + ny*Y + nz*Z (Heisenberg-rotated Z) ----

template<int M>
__device__ __forceinline__ float xy_inlane(const float (&vr)[16], const float (&vi)[16], float tnx, float tny) {
  float a = 0.f;
  #pragma unroll
  for (int j0 = 0; j0 < 16; ++j0) {
    if ((j0 & M) == 0) {
      const int j1 = j0 | M;
      float Re = fmaf(vr[j0], vr[j1], vi[j0] * vi[j1]);
      float Im = fmaf(vr[j0], vi[j1], -(vi[j0] * vr[j1]));
      a = fmaf(tnx, Re, a);
      a = fmaf(tny, Im, a);
    }
  }
  return a;
}

template<int MASK>
__device__ __forceinline__ float xy_cross(const float (&vr)[16], const float (&vi)[16], int l, float nx, float ny) {
  const float nys = (l & MASK) ? -ny : ny;   // Im(a0*.a1) flips sign on the b=1 side
  float a = 0.f;
  #pragma unroll
  for (int j = 0; j < 16; ++j) {
    float xr = lanex<MASK>(vr[j]), xi = lanex<MASK>(vi[j]);
    float Re  = fmaf(vr[j], xr, vi[j] * xi);
    float Imt = fmaf(vr[j], xi, -(vi[j] * xr));
    a = fmaf(nx, Re, a);
    a = fmaf(nys, Imt, a);
  }
  return a;   // summing both lanes of each pair supplies the factor 2
}

__global__ __launch_bounds__(256)
void qcnn_kernel(const float* __restrict__ x, const float* __restrict__ rl,
                 const float* __restrict__ thx, const float* __restrict__ thy,
                 float* __restrict__ out, OpList ops)
{
  const int tid = blockIdx.x * blockDim.x + threadIdx.x;
  const int b = tid >> 4;    // sample
  const int l = tid & 15;    // lane-in-group

  float vr[16], vi[16];

  // ---- layer 1: 8 per-sample RYs on |0..0> == product state, built directly ----
  float cw[8], sw[8];
  #pragma unroll
  for (int w = 0; w < 8; ++w) {
    const float a = x[b * 8 + w] * 0.5f;
    __sincosf(a, &sw[w], &cw[w]);
  }
  const float pl = ((l & 8) ? sw[4] : cw[4]) * ((l & 4) ? sw[5] : cw[5]) *
                   ((l & 2) ? sw[6] : cw[6]) * ((l & 1) ? sw[7] : cw[7]);
  #pragma unroll
  for (int j = 0; j < 16; ++j) {
    const float ph = ((j & 8) ? sw[0] : cw[0]) * ((j & 4) ? sw[1] : cw[1]) *
                     ((j & 2) ? sw[2] : cw[2]) * ((j & 1) ? sw[3] : cw[3]);
    vr[j] = ph * pl; vi[j] = 0.0f;
  }

  // ---- 20 RL ops (host-decoded, wave-uniform dispatch) ----
  for (int k = 0; k < NOPS; ++k) {
    const int kind = ops.kind[k];
    if (kind == 3) {
      apply_cnot_rt(ops.w0[k], ops.w1[k], vr, vi, l);
    } else {
      const float a = rl[k] * 0.5f;
      float sn, cs; __sincosf(a, &sn, &cs);
      if (kind == 2) apply_rz_rt(ops.w0[k], vr, vi, l, cs, sn);
      else           apply_rot_rt(kind, ops.w0[k], vr, vi, l, cs, sn);
    }
  }

  // ---- final RX/RY layer folded into the observable:
  //      M = nz*Z + ny*Y + nx*X  with full angles tx, ty ----
  float sx, cx, sy, cy;
  __sincosf(thx[0], &sx, &cx);
  __sincosf(thy[0], &sy, &cy);
  const float nx = -sy, ny = cy * sx, nz = cy * cx;
  const float tnx = 2.f * nx, tny = 2.f * ny;

  // Z parts: signed |amp|^2 sums
  float P = 0.f, A0 = 0.f, A1 = 0.f, A2 = 0.f, A3 = 0.f;
  #pragma unroll
  for (int j = 0; j < 16; ++j) {
    const float p = fmaf(vr[j], vr[j], vi[j] * vi[j]);
    P += p;
    A0 += (j & 8) ? -p : p;
    A1 += (j & 4) ? -p : p;
    A2 += (j & 2) ? -p : p;
    A3 += (j & 1) ? -p : p;
  }

  // per-wire expectations (per-lane partial sums; linear -> reduce at the end)
  float t0 = fmaf(nz, A0, xy_inlane<8>(vr, vi, tnx, tny));
  float t1 = fmaf(nz, A1, xy_inlane<4>(vr, vi, tnx, tny));
  float t2 = fmaf(nz, A2, xy_inlane<2>(vr, vi, tnx, tny));
  float t3 = fmaf(nz, A3, xy_inlane<1>(vr, vi, tnx, tny));
  float t4 = fmaf(nz, (l & 8) ? -P : P, xy_cross<8>(vr, vi, l, nx, ny));
  float t5 = fmaf(nz, (l & 4) ? -P : P, xy_cross<4>(vr, vi, l, nx, ny));
  float t6 = fmaf(nz, (l & 2) ? -P : P, xy_cross<2>(vr, vi, l, nx, ny));
  float t7 = fmaf(nz, (l & 1) ? -P : P, xy_cross<1>(vr, vi, l, nx, ny));

  // 16-lane butterfly reduction
  #define RED_STEP(MK) \
    t0 += lanex<MK>(t0); t1 += lanex<MK>(t1); t2 += lanex<MK>(t2); t3 += lanex<MK>(t3); \
    t4 += lanex<MK>(t4); t5 += lanex<MK>(t5); t6 += lanex<MK>(t6); t7 += lanex<MK>(t7);
  RED_STEP(1) RED_STEP(2) RED_STEP(4) RED_STEP(8)
  #undef RED_STEP

  if (l == 0) {
    float* o = out + b * 8;
    o[0] = t0; o[1] = t1; o[2] = t2; o[3] = t3;
    o[4] = t4; o[5] = t5; o[6] = t6; o[7] = t7;
  }
}

// ---------------- host side: replicate np.random.RandomState(0) op list ----------------

namespace {

struct NpMT {
  uint32_t mt[624];
  int pos;
  explicit NpMT(uint32_t seed) {
    for (int i = 0; i < 624; ++i) {
      mt[i] = seed;
      seed = 1812433253u * (seed ^ (seed >> 30)) + (uint32_t)(i + 1);
    }
    pos = 624;
  }
  uint32_t next32() {
    if (pos >= 624) {
      for (int i = 0; i < 624; ++i) {
        uint32_t y = (mt[i] & 0x80000000u) | (mt[(i + 1) % 624] & 0x7fffffffu);
        mt[i] = mt[(i + 397) % 624] ^ (y >> 1) ^ ((y & 1u) ? 0x9908b0dfu : 0u);
      }
      pos = 0;
    }
    uint32_t y = mt[pos++];
    y ^= y >> 11;
    y ^= (y << 7) & 0x9d2c5680u;
    y ^= (y << 15) & 0xefc60000u;
    y ^= y >> 18;
    return y;
  }
  uint32_t interval(uint32_t mx) {  // uniform in [0, mx] inclusive (legacy masked rejection)
    if (mx == 0u) return 0u;
    uint32_t mask = mx;
    mask |= mask >> 1; mask |= mask >> 2; mask |= mask >> 4; mask |= mask >> 8; mask |= mask >> 16;
    uint32_t v;
    do { v = next32() & mask; } while (v > mx);
    return v;
  }
};

void decode_ops(OpList& ops) {
  NpMT r(0u);
  for (int k = 0; k < NOPS; ++k) {
    const uint32_t kind = r.interval(3u);          // randint(4)
    ops.kind[k] = (int)kind;
    if (kind == 3u) {                              // choice(8,2,replace=False) == permutation(8)[:2]
      int perm[NQ];
      for (int i = 0; i < NQ; ++i) perm[i] = i;
      for (int i = NQ - 1; i >= 1; --i) {
        const uint32_t j = r.interval((uint32_t)i);
        const int t = perm[i]; perm[i] = perm[(int)j]; perm[(int)j] = t;
      }
      ops.w0[k] = perm[0];
      ops.w1[k] = perm[1];
    } else {
      ops.w0[k] = (int)r.interval(7u);             // randint(8)
      ops.w1[k] = -1;
    }
  }
}

} // namespace

extern "C" void kernel_launch(void* const* d_in, const int* in_sizes, int n_in,
                              void* d_out, int out_size, void* d_ws, size_t ws_size,
                              hipStream_t stream) {
  const float* x   = (const float*)d_in[0];
  const float* rl  = (const float*)d_in[1];
  const float* thx = (const float*)d_in[2];
  const float* thy = (const float*)d_in[3];
  float* out = (float*)d_out;

  OpList ops;
  decode_ops(ops);  // deterministic on every call

  const int threads = 256;                  // 4 waves, 16 samples per block
  const int blocks = BSZ / (threads / 16);  // 2048
  qcnn_kernel<<<blocks, threads, 0, stream>>>(x, rl, thx, thy, out, ops);
}

// Round 3
// 25.772 us; speedup vs baseline: 2.4474x; 1.5906x over previous
//
#include <hip/hip_runtime.h>
#include <stdint.h>

#define NQ 8
#define DIM 256
#define BSZ 32768
#define NOPS 20

typedef float v2f __attribute__((ext_vector_type(2)));

// ================= compile-time replication of np.random.RandomState(0) =================

struct COps { int kind[NOPS]; int w0[NOPS]; int w1[NOPS]; };

struct CMT {
  uint32_t mt[624]; int pos;
  constexpr CMT(uint32_t seed) : mt{}, pos(624) {
    for (int i = 0; i < 624; ++i) {
      mt[i] = seed;
      seed = 1812433253u * (seed ^ (seed >> 30)) + (uint32_t)(i + 1);
    }
  }
  constexpr uint32_t next32() {
    if (pos >= 624) {
      for (int i = 0; i < 624; ++i) {
        uint32_t y = (mt[i] & 0x80000000u) | (mt[(i + 1) % 624] & 0x7fffffffu);
        mt[i] = mt[(i + 397) % 624] ^ (y >> 1) ^ ((y & 1u) ? 0x9908b0dfu : 0u);
      }
      pos = 0;
    }
    uint32_t y = mt[pos++];
    y ^= y >> 11; y ^= (y << 7) & 0x9d2c5680u; y ^= (y << 15) & 0xefc60000u; y ^= y >> 18;
    return y;
  }
  constexpr uint32_t interval(uint32_t mx) {  // legacy masked rejection, [0, mx]
    if (mx == 0u) return 0u;
    uint32_t mask = mx;
    mask |= mask >> 1; mask |= mask >> 2; mask |= mask >> 4; mask |= mask >> 8; mask |= mask >> 16;
    uint32_t v = next32() & mask;
    while (v > mx) v = next32() & mask;
    return v;
  }
};

constexpr COps decode_ops() {
  COps o{}; CMT r(0u);
  for (int k = 0; k < NOPS; ++k) {
    const uint32_t kind = r.interval(3u);            // randint(4)
    o.kind[k] = (int)kind;
    if (kind == 3u) {                                // choice(8,2,False) == permutation(8)[:2]
      int perm[NQ] = {0,1,2,3,4,5,6,7};
      for (int i = NQ - 1; i >= 1; --i) {
        const uint32_t j = r.interval((uint32_t)i);
        const int t = perm[i]; perm[i] = perm[(int)j]; perm[(int)j] = t;
      }
      o.w0[k] = perm[0]; o.w1[k] = perm[1];
    } else {
      o.w0[k] = (int)r.interval(7u);                 // randint(8)
      o.w1[k] = -1;
    }
  }
  return o;
}

constexpr COps OPS = decode_ops();

// ================= device helpers =================

// Cross-lane XOR exchange within 16-lane groups (32-bit).
template<int MASK>
__device__ __forceinline__ float lanexf(float v) {
  int i = __builtin_bit_cast(int, v);
  int r;
  if constexpr (MASK == 1)      r = __builtin_amdgcn_update_dpp(0, i, 0xB1, 0xF, 0xF, true);  // quad_perm(1,0,3,2)
  else if constexpr (MASK == 2) r = __builtin_amdgcn_update_dpp(0, i, 0x4E, 0xF, 0xF, true);  // quad_perm(2,3,0,1)
  else if constexpr (MASK == 8) r = __builtin_amdgcn_update_dpp(0, i, 0x128, 0xF, 0xF, true); // row_ror:8
  else                          r = __builtin_amdgcn_ds_swizzle(i, 0x101F);                   // xor4
  return __builtin_bit_cast(float, r);
}

template<int MASK>
__device__ __forceinline__ v2f lanex2(v2f v) {
  v2f r; r.x = lanexf<MASK>(v.x); r.y = lanexf<MASK>(v.y); return r;
}

__device__ __forceinline__ v2f vswap(v2f v) { return __builtin_shufflevector(v, v, 1, 0); }
__device__ __forceinline__ v2f vsplat(float s) { v2f r = {s, s}; return r; }

// Layout: amplitude d = (j<<4)|l ; wire w -> mask m = 1<<(7-w) in d.
// m >= 16: in-lane pair (j0, j0|m>>4) ; m < 16: cross-lane via lanex2<m>.

template<int W>
__device__ __forceinline__ void g_rx(v2f (&v)[16], int l, float c, float s) {
  constexpr int m = 1 << (7 - W);
  const v2f vc = vsplat(c);
  const v2f spm = {s, -s};
  if constexpr (m >= 16) {
    constexpr int M = m >> 4;
    #pragma unroll
    for (int j0 = 0; j0 < 16; ++j0) if ((j0 & M) == 0) {
      const int j1 = j0 | M;
      v2f a = v[j0], b = v[j1];
      v[j0] = vc * a + spm * vswap(b);   // (c r0 + s i1, c i0 - s r1)
      v[j1] = vc * b + spm * vswap(a);
    }
  } else {
    #pragma unroll
    for (int j = 0; j < 16; ++j) {
      v2f x = lanex2<m>(v[j]);
      v[j] = vc * v[j] + spm * vswap(x);
    }
  }
}

template<int W>
__device__ __forceinline__ void g_ry(v2f (&v)[16], int l, float c, float s) {
  constexpr int m = 1 << (7 - W);
  const v2f vc = vsplat(c), vs = vsplat(s);
  if constexpr (m >= 16) {
    constexpr int M = m >> 4;
    #pragma unroll
    for (int j0 = 0; j0 < 16; ++j0) if ((j0 & M) == 0) {
      const int j1 = j0 | M;
      v2f a = v[j0], b = v[j1];
      v[j0] = vc * a - vs * b;
      v[j1] = vc * b + vs * a;
    }
  } else {
    const v2f t = vsplat((l & m) ? s : -s);
    #pragma unroll
    for (int j = 0; j < 16; ++j) {
      v2f x = lanex2<m>(v[j]);
      v[j] = vc * v[j] + t * x;
    }
  }
}

template<int W>
__device__ __forceinline__ void g_rz(v2f (&v)[16], int l, float c, float s) {
  constexpr int m = 1 << (7 - W);
  const v2f vc = vsplat(c);
  if constexpr (m >= 16) {
    constexpr int M = m >> 4;
    const v2f spm = {s, -s};
    #pragma unroll
    for (int j = 0; j < 16; ++j) {
      v2f sw = vswap(v[j]);
      if ((j & M) == 0) v[j] = vc * v[j] + spm * sw;  // *(c - i s)
      else              v[j] = vc * v[j] - spm * sw;  // *(c + i s)
    }
  } else {
    const v2f t = (l & m) ? (v2f){-s, s} : (v2f){s, -s};
    #pragma unroll
    for (int j = 0; j < 16; ++j) v[j] = vc * v[j] + t * vswap(v[j]);
  }
}

template<int WC, int WT>
__device__ __forceinline__ void g_cnot(v2f (&v)[16], int l) {
  constexpr int mc = 1 << (7 - WC);
  constexpr int mt = 1 << (7 - WT);
  if constexpr (mt >= 16) {           // in-lane target
    constexpr int M = mt >> 4;
    if constexpr (mc >= 16) {         // j-control: pure register rename, zero instructions
      constexpr int MC = mc >> 4;
      #pragma unroll
      for (int j0 = 0; j0 < 16; ++j0) if ((j0 & M) == 0 && (j0 & MC) != 0) {
        const int j1 = j0 | M;
        v2f t = v[j0]; v[j0] = v[j1]; v[j1] = t;
      }
    } else {                          // lane-control: per-lane select
      const bool bit = (l & mc) != 0;
      #pragma unroll
      for (int j0 = 0; j0 < 16; ++j0) if ((j0 & M) == 0) {
        const int j1 = j0 | M;
        v2f a = v[j0], b = v[j1];
        v[j0] = bit ? b : a;
        v[j1] = bit ? a : b;
      }
    }
  } else {                            // cross-lane target
    if constexpr (mc >= 16) {         // j-control: exchange only controlled j's
      constexpr int MC = mc >> 4;
      #pragma unroll
      for (int j = 0; j < 16; ++j) if (j & MC) v[j] = lanex2<mt>(v[j]);
    } else if constexpr ((mc == 8 || mc == 4) && mt != 4) {
      // lane-control on a bank boundary: bank-masked DPP, no cndmask.
      constexpr int BM   = (mc == 8) ? 0xC : 0xA;                      // banks where control=1
      constexpr int ctrl = (mt == 1) ? 0xB1 : (mt == 2) ? 0x4E : 0x128;
      #pragma unroll
      for (int j = 0; j < 16; ++j) {
        int ir = __builtin_bit_cast(int, v[j].x);
        int ii = __builtin_bit_cast(int, v[j].y);
        ir = __builtin_amdgcn_update_dpp(ir, ir, ctrl, 0xF, BM, false);
        ii = __builtin_amdgcn_update_dpp(ii, ii, ctrl, 0xF, BM, false);
        v[j].x = __builtin_bit_cast(float, ir);
        v[j].y = __builtin_bit_cast(float, ii);
      }
    } else {                          // lane-control, general
      const bool bit = (l & mc) != 0;
      #pragma unroll
      for (int j = 0; j < 16; ++j) {
        v2f x = lanex2<mt>(v[j]);
        v[j] = bit ? x : v[j];
      }
    }
  }
}

// fully unrolled, compile-time op sequence
template<int K>
__device__ __forceinline__ void apply_ops(v2f (&v)[16], int l, const float* __restrict__ rl) {
  if constexpr (K < NOPS) {
    constexpr int kind = OPS.kind[K];
    if constexpr (kind == 3) {
      g_cnot<OPS.w0[K], OPS.w1[K]>(v, l);
    } else {
      float sn, cs;
      __sincosf(0.5f * rl[K], &sn, &cs);
      if constexpr      (kind == 0) g_rx<OPS.w0[K]>(v, l, cs, sn);
      else if constexpr (kind == 1) g_ry<OPS.w0[K]>(v, l, cs, sn);
      else                          g_rz<OPS.w0[K]>(v, l, cs, sn);
    }
    apply_ops<K + 1>(v, l, rl);
  }
}

// ---- observable: M = nx*X + ny*Y + nz*Z per wire (final RX/RY folded in) ----

template<int M>
__device__ __forceinline__ float xy_inlane(const v2f (&v)[16], float tnx, float tny) {
  v2f aRe = {0.f, 0.f}, aIm = {0.f, 0.f};
  #pragma unroll
  for (int j0 = 0; j0 < 16; ++j0) if ((j0 & M) == 0) {
    const int j1 = j0 | M;
    aRe += v[j0] * v[j1];          // (r0 r1, i0 i1)
    aIm += v[j0] * vswap(v[j1]);   // (r0 i1, i0 r1)
  }
  return tnx * (aRe.x + aRe.y) + tny * (aIm.x - aIm.y);
}

template<int MASK>
__device__ __forceinline__ float xy_cross(const v2f (&v)[16], int l, float nx, float ny) {
  v2f aRe = {0.f, 0.f}, aIm = {0.f, 0.f};
  #pragma unroll
  for (int j = 0; j < 16; ++j) {
    v2f x = lanex2<MASK>(v[j]);
    aRe += v[j] * x;
    aIm += v[j] * vswap(x);
  }
  const float nys = (l & MASK) ? -ny : ny;
  return nx * (aRe.x + aRe.y) + nys * (aIm.x - aIm.y);  // both lanes summed -> factor 2
}

__global__ __launch_bounds__(256)
void qcnn_kernel(const float* __restrict__ x, const float* __restrict__ rl,
                 const float* __restrict__ thx, const float* __restrict__ thy,
                 float* __restrict__ out)
{
  const int tid = blockIdx.x * blockDim.x + threadIdx.x;
  const int b = tid >> 4;
  const int l = tid & 15;

  // ---- init: product state from first RY layer, vectorized loads ----
  const float4* xp = reinterpret_cast<const float4*>(x + (size_t)b * 8);
  const float4 xa = xp[0], xb = xp[1];
  float sw[8], cw[8];
  __sincosf(0.5f * xa.x, &sw[0], &cw[0]);
  __sincosf(0.5f * xa.y, &sw[1], &cw[1]);
  __sincosf(0.5f * xa.z, &sw[2], &cw[2]);
  __sincosf(0.5f * xa.w, &sw[3], &cw[3]);
  __sincosf(0.5f * xb.x, &sw[4], &cw[4]);
  __sincosf(0.5f * xb.y, &sw[5], &cw[5]);
  __sincosf(0.5f * xb.z, &sw[6], &cw[6]);
  __sincosf(0.5f * xb.w, &sw[7], &cw[7]);

  const float pl = ((l & 8) ? sw[4] : cw[4]) * ((l & 4) ? sw[5] : cw[5]) *
                   ((l & 2) ? sw[6] : cw[6]) * ((l & 1) ? sw[7] : cw[7]);
  const float p01[4] = {cw[0]*cw[1], cw[0]*sw[1], sw[0]*cw[1], sw[0]*sw[1]};
  const float p23[4] = {cw[2]*cw[3], cw[2]*sw[3], sw[2]*cw[3], sw[2]*sw[3]};
  const float p01l[4] = {p01[0]*pl, p01[1]*pl, p01[2]*pl, p01[3]*pl};

  v2f v[16];
  #pragma unroll
  for (int j = 0; j < 16; ++j) { v[j].x = p01l[j >> 2] * p23[j & 3]; v[j].y = 0.f; }

  // ---- 20 compile-time gates ----
  apply_ops<0>(v, l, rl);

  // ---- folded final RX/RY layer: observable direction ----
  float sxf, cxf, syf, cyf;
  __sincosf(thx[0], &sxf, &cxf);
  __sincosf(thy[0], &syf, &cyf);
  const float nx = -syf, ny = cyf * sxf, nz = cyf * cxf;
  const float tnx = 2.f * nx, tny = 2.f * ny;

  // Z parts: signed |amp|^2 sums (packed accumulate, compile-time signs)
  v2f P2 = {0,0}, A0v = {0,0}, A1v = {0,0}, A2v = {0,0}, A3v = {0,0};
  #pragma unroll
  for (int j = 0; j < 16; ++j) {
    const v2f q = v[j] * v[j];
    P2 += q;
    if (j & 8) A0v -= q; else A0v += q;
    if (j & 4) A1v -= q; else A1v += q;
    if (j & 2) A2v -= q; else A2v += q;
    if (j & 1) A3v -= q; else A3v += q;
  }
  const float P  = P2.x + P2.y;
  const float A0 = A0v.x + A0v.y, A1 = A1v.x + A1v.y;
  const float A2 = A2v.x + A2v.y, A3 = A3v.x + A3v.y;

  float t0 = fmaf(nz, A0, xy_inlane<8>(v, tnx, tny));
  float t1 = fmaf(nz, A1, xy_inlane<4>(v, tnx, tny));
  float t2 = fmaf(nz, A2, xy_inlane<2>(v, tnx, tny));
  float t3 = fmaf(nz, A3, xy_inlane<1>(v, tnx, tny));
  float t4 = fmaf(nz, (l & 8) ? -P : P, xy_cross<8>(v, l, nx, ny));
  float t5 = fmaf(nz, (l & 4) ? -P : P, xy_cross<4>(v, l, nx, ny));
  float t6 = fmaf(nz, (l & 2) ? -P : P, xy_cross<2>(v, l, nx, ny));
  float t7 = fmaf(nz, (l & 1) ? -P : P, xy_cross<1>(v, l, nx, ny));

  #define RED_STEP(MK) \
    t0 += lanexf<MK>(t0); t1 += lanexf<MK>(t1); t2 += lanexf<MK>(t2); t3 += lanexf<MK>(t3); \
    t4 += lanexf<MK>(t4); t5 += lanexf<MK>(t5); t6 += lanexf<MK>(t6); t7 += lanexf<MK>(t7);
  RED_STEP(1) RED_STEP(2) RED_STEP(4) RED_STEP(8)
  #undef RED_STEP

  if (l == 0) {
    float4* o = reinterpret_cast<float4*>(out + (size_t)b * 8);
    const float4 o0 = {t0, t1, t2, t3};
    const float4 o1 = {t4, t5, t6, t7};
    o[0] = o0; o[1] = o1;
  }
}

// ================= host =================

extern "C" void kernel_launch(void* const* d_in, const int* in_sizes, int n_in,
                              void* d_out, int out_size, void* d_ws, size_t ws_size,
                              hipStream_t stream) {
  const float* x   = (const float*)d_in[0];
  const float* rl  = (const float*)d_in[1];
  const float* thx = (const float*)d_in[2];
  const float* thy = (const float*)d_in[3];
  float* out = (float*)d_out;

  const int threads = 256;                  // 4 waves, 16 samples per block
  const int blocks = BSZ / (threads / 16);  // 2048
  qcnn_kernel<<<blocks, threads, 0, stream>>>(x, rl, thx, thy, out);
}

// Round 4
// 24.015 us; speedup vs baseline: 2.6264x; 1.0731x over previous
//
#include <hip/hip_runtime.h>
#include <stdint.h>

#define NQ 8
#define DIM 256
#define BSZ 32768
#define NOPS 20

typedef float v2f __attribute__((ext_vector_type(2)));

// ================= compile-time replication of np.random.RandomState(0) =================

struct COps { int kind[NOPS]; int w0[NOPS]; int w1[NOPS]; };

struct CMT {
  uint32_t mt[624]; int pos;
  constexpr CMT(uint32_t seed) : mt{}, pos(624) {
    for (int i = 0; i < 624; ++i) {
      mt[i] = seed;
      seed = 1812433253u * (seed ^ (seed >> 30)) + (uint32_t)(i + 1);
    }
  }
  constexpr uint32_t next32() {
    if (pos >= 624) {
      for (int i = 0; i < 624; ++i) {
        uint32_t y = (mt[i] & 0x80000000u) | (mt[(i + 1) % 624] & 0x7fffffffu);
        mt[i] = mt[(i + 397) % 624] ^ (y >> 1) ^ ((y & 1u) ? 0x9908b0dfu : 0u);
      }
      pos = 0;
    }
    uint32_t y = mt[pos++];
    y ^= y >> 11; y ^= (y << 7) & 0x9d2c5680u; y ^= (y << 15) & 0xefc60000u; y ^= y >> 18;
    return y;
  }
  constexpr uint32_t interval(uint32_t mx) {  // legacy masked rejection, [0, mx]
    if (mx == 0u) return 0u;
    uint32_t mask = mx;
    mask |= mask >> 1; mask |= mask >> 2; mask |= mask >> 4; mask |= mask >> 8; mask |= mask >> 16;
    uint32_t v = next32() & mask;
    while (v > mx) v = next32() & mask;
    return v;
  }
};

constexpr COps decode_ops() {
  COps o{}; CMT r(0u);
  for (int k = 0; k < NOPS; ++k) {
    const uint32_t kind = r.interval(3u);            // randint(4)
    o.kind[k] = (int)kind;
    if (kind == 3u) {                                // choice(8,2,False) == permutation(8)[:2]
      int perm[NQ] = {0,1,2,3,4,5,6,7};
      for (int i = NQ - 1; i >= 1; --i) {
        const uint32_t j = r.interval((uint32_t)i);
        const int t = perm[i]; perm[i] = perm[(int)j]; perm[(int)j] = t;
      }
      o.w0[k] = perm[0]; o.w1[k] = perm[1];
    } else {
      o.w0[k] = (int)r.interval(7u);                 // randint(8)
      o.w1[k] = -1;
    }
  }
  return o;
}

constexpr COps OPS = decode_ops();

// ================= device helpers =================

// Cross-lane XOR exchange within 16-lane groups (32-bit).
template<int MASK>
__device__ __forceinline__ float lanexf(float v) {
  int i = __builtin_bit_cast(int, v);
  int r;
  if constexpr (MASK == 1)      r = __builtin_amdgcn_update_dpp(0, i, 0xB1, 0xF, 0xF, true);  // quad_perm(1,0,3,2)
  else if constexpr (MASK == 2) r = __builtin_amdgcn_update_dpp(0, i, 0x4E, 0xF, 0xF, true);  // quad_perm(2,3,0,1)
  else if constexpr (MASK == 8) r = __builtin_amdgcn_update_dpp(0, i, 0x128, 0xF, 0xF, true); // row_ror:8
  else                          r = __builtin_amdgcn_ds_swizzle(i, 0x101F);                   // xor4
  return __builtin_bit_cast(float, r);
}

template<int MASK>
__device__ __forceinline__ v2f lanex2(v2f v) {
  v2f r; r.x = lanexf<MASK>(v.x); r.y = lanexf<MASK>(v.y); return r;
}

__device__ __forceinline__ v2f vswap(v2f v) { return __builtin_shufflevector(v, v, 1, 0); }
__device__ __forceinline__ v2f vsplat(float s) { v2f r = {s, s}; return r; }

// Layout: amplitude d = (j<<4)|l ; wire w -> mask m = 1<<(7-w) in d.
// m >= 16: in-lane pair (j0, j0|m>>4) ; m < 16: cross-lane via lanex2<m>.
//
// Tan-form gates: U = c(I + t G). Only (I + t G) is applied (1 pk_fma per
// element); the c factors accumulate into a global constant applied to the
// observable as C^2 (expectations are quadratic in the state).

template<int W>
__device__ __forceinline__ void g_rx_t(v2f (&v)[16], int l, float t) {
  constexpr int m = 1 << (7 - W);
  const v2f tpm = {t, -t};
  if constexpr (m >= 16) {
    constexpr int M = m >> 4;
    #pragma unroll
    for (int j0 = 0; j0 < 16; ++j0) if ((j0 & M) == 0) {
      const int j1 = j0 | M;
      v2f a = v[j0], b = v[j1];
      v[j0] = a + tpm * vswap(b);   // (r0 + t i1, i0 - t r1)
      v[j1] = b + tpm * vswap(a);
    }
  } else {
    #pragma unroll
    for (int j = 0; j < 16; ++j) {
      v2f x = lanex2<m>(v[j]);
      v[j] = v[j] + tpm * vswap(x);
    }
  }
}

template<int W>
__device__ __forceinline__ void g_ry_t(v2f (&v)[16], int l, float t) {
  constexpr int m = 1 << (7 - W);
  if constexpr (m >= 16) {
    constexpr int M = m >> 4;
    const v2f vtn = vsplat(-t), vtp = vsplat(t);
    #pragma unroll
    for (int j0 = 0; j0 < 16; ++j0) if ((j0 & M) == 0) {
      const int j1 = j0 | M;
      v2f a = v[j0], b = v[j1];
      v[j0] = a + vtn * b;
      v[j1] = b + vtp * a;
    }
  } else {
    const v2f ts = vsplat((l & m) ? t : -t);
    #pragma unroll
    for (int j = 0; j < 16; ++j) {
      v2f x = lanex2<m>(v[j]);
      v[j] = v[j] + ts * x;
    }
  }
}

template<int W>
__device__ __forceinline__ void g_rz_t(v2f (&v)[16], int l, float t) {
  constexpr int m = 1 << (7 - W);
  if constexpr (m >= 16) {
    constexpr int M = m >> 4;
    const v2f tpm = {t, -t};
    #pragma unroll
    for (int j = 0; j < 16; ++j) {
      v2f sw = vswap(v[j]);
      if ((j & M) == 0) v[j] = v[j] + tpm * sw;   // *(1 - i t)
      else              v[j] = v[j] - tpm * sw;   // *(1 + i t)
    }
  } else {
    const v2f ts = (l & m) ? (v2f){-t, t} : (v2f){t, -t};
    #pragma unroll
    for (int j = 0; j < 16; ++j) v[j] = v[j] + ts * vswap(v[j]);
  }
}

template<int WC, int WT>
__device__ __forceinline__ void g_cnot(v2f (&v)[16], int l) {
  constexpr int mc = 1 << (7 - WC);
  constexpr int mt = 1 << (7 - WT);
  if constexpr (mt >= 16) {           // in-lane target
    constexpr int M = mt >> 4;
    if constexpr (mc >= 16) {         // j-control: pure register rename, zero instructions
      constexpr int MC = mc >> 4;
      #pragma unroll
      for (int j0 = 0; j0 < 16; ++j0) if ((j0 & M) == 0 && (j0 & MC) != 0) {
        const int j1 = j0 | M;
        v2f t = v[j0]; v[j0] = v[j1]; v[j1] = t;
      }
    } else {                          // lane-control: per-lane select
      const bool bit = (l & mc) != 0;
      #pragma unroll
      for (int j0 = 0; j0 < 16; ++j0) if ((j0 & M) == 0) {
        const int j1 = j0 | M;
        v2f a = v[j0], b = v[j1];
        v[j0] = bit ? b : a;
        v[j1] = bit ? a : b;
      }
    }
  } else {                            // cross-lane target
    if constexpr (mc >= 16) {         // j-control: exchange only controlled j's
      constexpr int MC = mc >> 4;
      #pragma unroll
      for (int j = 0; j < 16; ++j) if (j & MC) v[j] = lanex2<mt>(v[j]);
    } else if constexpr ((mc == 8 || mc == 4) && mt != 4) {
      // lane-control on a bank boundary: bank-masked DPP, no cndmask.
      constexpr int BM   = (mc == 8) ? 0xC : 0xA;                      // banks where control=1
      constexpr int ctrl = (mt == 1) ? 0xB1 : (mt == 2) ? 0x4E : 0x128;
      #pragma unroll
      for (int j = 0; j < 16; ++j) {
        int ir = __builtin_bit_cast(int, v[j].x);
        int ii = __builtin_bit_cast(int, v[j].y);
        ir = __builtin_amdgcn_update_dpp(ir, ir, ctrl, 0xF, BM, false);
        ii = __builtin_amdgcn_update_dpp(ii, ii, ctrl, 0xF, BM, false);
        v[j].x = __builtin_bit_cast(float, ir);
        v[j].y = __builtin_bit_cast(float, ii);
      }
    } else {                          // lane-control, general
      const bool bit = (l & mc) != 0;
      #pragma unroll
      for (int j = 0; j < 16; ++j) {
        v2f x = lanex2<mt>(v[j]);
        v[j] = bit ? x : v[j];
      }
    }
  }
}

// fully unrolled, compile-time op sequence; cacc accumulates the deferred cos factors
template<int K>
__device__ __forceinline__ void apply_ops(v2f (&v)[16], int l, const float* __restrict__ rl, float& cacc) {
  if constexpr (K < NOPS) {
    constexpr int kind = OPS.kind[K];
    if constexpr (kind == 3) {
      g_cnot<OPS.w0[K], OPS.w1[K]>(v, l);
    } else {
      float sn, cs;
      __sincosf(0.5f * rl[K], &sn, &cs);
      const float t = sn * __builtin_amdgcn_rcpf(cs);
      cacc *= cs;
      if constexpr      (kind == 0) g_rx_t<OPS.w0[K]>(v, l, t);
      else if constexpr (kind == 1) g_ry_t<OPS.w0[K]>(v, l, t);
      else                          g_rz_t<OPS.w0[K]>(v, l, t);
    }
    apply_ops<K + 1>(v, l, rl, cacc);
  }
}

// ---- observable: M = nx*X + ny*Y + nz*Z per wire (final RX/RY folded in) ----

template<int M>
__device__ __forceinline__ float xy_inlane(const v2f (&v)[16], float tnx, float tny) {
  v2f aRe = {0.f, 0.f}, aIm = {0.f, 0.f};
  #pragma unroll
  for (int j0 = 0; j0 < 16; ++j0) if ((j0 & M) == 0) {
    const int j1 = j0 | M;
    aRe += v[j0] * v[j1];          // (r0 r1, i0 i1)
    aIm += v[j0] * vswap(v[j1]);   // (r0 i1, i0 r1)
  }
  return tnx * (aRe.x + aRe.y) + tny * (aIm.x - aIm.y);
}

template<int MASK>
__device__ __forceinline__ float xy_cross(const v2f (&v)[16], int l, float nx, float ny) {
  v2f aRe = {0.f, 0.f}, aIm = {0.f, 0.f};
  #pragma unroll
  for (int j = 0; j < 16; ++j) {
    v2f x = lanex2<MASK>(v[j]);
    aRe += v[j] * x;
    aIm += v[j] * vswap(x);
  }
  const float nys = (l & MASK) ? -ny : ny;
  return nx * (aRe.x + aRe.y) + nys * (aIm.x - aIm.y);  // both lanes summed -> factor 2
}

__global__ __launch_bounds__(256)
void qcnn_kernel(const float* __restrict__ x, const float* __restrict__ rl,
                 const float* __restrict__ thx, const float* __restrict__ thy,
                 float* __restrict__ out)
{
  const int tid = blockIdx.x * blockDim.x + threadIdx.x;
  const int b = tid >> 4;
  const int l = tid & 15;

  // ---- init: product state from first RY layer, vectorized loads ----
  const float4* xp = reinterpret_cast<const float4*>(x + (size_t)b * 8);
  const float4 xa = xp[0], xb = xp[1];
  float sw[8], cw[8];
  __sincosf(0.5f * xa.x, &sw[0], &cw[0]);
  __sincosf(0.5f * xa.y, &sw[1], &cw[1]);
  __sincosf(0.5f * xa.z, &sw[2], &cw[2]);
  __sincosf(0.5f * xa.w, &sw[3], &cw[3]);
  __sincosf(0.5f * xb.x, &sw[4], &cw[4]);
  __sincosf(0.5f * xb.y, &sw[5], &cw[5]);
  __sincosf(0.5f * xb.z, &sw[6], &cw[6]);
  __sincosf(0.5f * xb.w, &sw[7], &cw[7]);

  const float pl = ((l & 8) ? sw[4] : cw[4]) * ((l & 4) ? sw[5] : cw[5]) *
                   ((l & 2) ? sw[6] : cw[6]) * ((l & 1) ? sw[7] : cw[7]);
  const float p01[4] = {cw[0]*cw[1], cw[0]*sw[1], sw[0]*cw[1], sw[0]*sw[1]};
  const float p23[4] = {cw[2]*cw[3], cw[2]*sw[3], sw[2]*cw[3], sw[2]*sw[3]};
  const float p01l[4] = {p01[0]*pl, p01[1]*pl, p01[2]*pl, p01[3]*pl};

  v2f v[16];
  #pragma unroll
  for (int j = 0; j < 16; ++j) { v[j].x = p01l[j >> 2] * p23[j & 3]; v[j].y = 0.f; }

  // ---- 20 compile-time gates (tan form, deferred cos product) ----
  float cacc = 1.0f;
  apply_ops<0>(v, l, rl, cacc);
  const float C2 = cacc * cacc;

  // ---- folded final RX/RY layer: observable direction, scaled by C^2 ----
  float sxf, cxf, syf, cyf;
  __sincosf(thx[0], &sxf, &cxf);
  __sincosf(thy[0], &syf, &cyf);
  const float nx = -syf * C2, ny = cyf * sxf * C2, nz = cyf * cxf * C2;
  const float tnx = 2.f * nx, tny = 2.f * ny;

  // Z parts: signed |amp|^2 sums (packed accumulate, compile-time signs)
  v2f P2 = {0,0}, A0v = {0,0}, A1v = {0,0}, A2v = {0,0}, A3v = {0,0};
  #pragma unroll
  for (int j = 0; j < 16; ++j) {
    const v2f q = v[j] * v[j];
    P2 += q;
    if (j & 8) A0v -= q; else A0v += q;
    if (j & 4) A1v -= q; else A1v += q;
    if (j & 2) A2v -= q; else A2v += q;
    if (j & 1) A3v -= q; else A3v += q;
  }
  const float P  = P2.x + P2.y;
  const float A0 = A0v.x + A0v.y, A1 = A1v.x + A1v.y;
  const float A2 = A2v.x + A2v.y, A3 = A3v.x + A3v.y;

  float t0 = fmaf(nz, A0, xy_inlane<8>(v, tnx, tny));
  float t1 = fmaf(nz, A1, xy_inlane<4>(v, tnx, tny));
  float t2 = fmaf(nz, A2, xy_inlane<2>(v, tnx, tny));
  float t3 = fmaf(nz, A3, xy_inlane<1>(v, tnx, tny));
  float t4 = fmaf(nz, (l & 8) ? -P : P, xy_cross<8>(v, l, nx, ny));
  float t5 = fmaf(nz, (l & 4) ? -P : P, xy_cross<4>(v, l, nx, ny));
  float t6 = fmaf(nz, (l & 2) ? -P : P, xy_cross<2>(v, l, nx, ny));
  float t7 = fmaf(nz, (l & 1) ? -P : P, xy_cross<1>(v, l, nx, ny));

  #define RED_STEP(MK) \
    t0 += lanexf<MK>(t0); t1 += lanexf<MK>(t1); t2 += lanexf<MK>(t2); t3 += lanexf<MK>(t3); \
    t4 += lanexf<MK>(t4); t5 += lanexf<MK>(t5); t6 += lanexf<MK>(t6); t7 += lanexf<MK>(t7);
  RED_STEP(1) RED_STEP(2) RED_STEP(4) RED_STEP(8)
  #undef RED_STEP

  if (l == 0) {
    float4* o = reinterpret_cast<float4*>(out + (size_t)b * 8);
    const float4 o0 = {t0, t1, t2, t3};
    const float4 o1 = {t4, t5, t6, t7};
    o[0] = o0; o[1] = o1;
  }
}

// ================= host =================

extern "C" void kernel_launch(void* const* d_in, const int* in_sizes, int n_in,
                              void* d_out, int out_size, void* d_ws, size_t ws_size,
                              hipStream_t stream) {
  const float* x   = (const float*)d_in[0];
  const float* rl  = (const float*)d_in[1];
  const float* thx = (const float*)d_in[2];
  const float* thy = (const float*)d_in[3];
  float* out = (float*)d_out;

  const int threads = 256;                  // 4 waves, 16 samples per block
  const int blocks = BSZ / (threads / 16);  // 2048
  qcnn_kernel<<<blocks, threads, 0, stream>>>(x, rl, thx, thy, out);
}